// Round 13
// baseline (315.125 us; speedup 1.0000x reference)
//
#include <hip/hip_runtime.h>
#include <stdint.h>

#define N_NODES 6144
#define LOG2E 1.44269504088896f

typedef float f32x4 __attribute__((ext_vector_type(4)));
typedef short short8 __attribute__((ext_vector_type(8)));
typedef unsigned int uint32;
typedef unsigned long long uint64;

extern "C" __device__ float __ocml_native_exp2_f32(float);

// pack two floats -> two bf16 (round-half-up) in one u32: lo=a, hi=b
__device__ __forceinline__ unsigned int pack2bf(float a, float b) {
  unsigned int ua = __float_as_uint(a) + 0x8000u;
  unsigned int ub = __float_as_uint(b) + 0x8000u;
  return __builtin_amdgcn_perm(ub, ua, 0x07060302u);
}

// K0: bit-pack adjacency via wave ballot. Lane reads ONE int (coalesced
// 256B per wave instr), ballot packs 64 edges, one lane stores the u64.
__global__ __launch_bounds__(256) void k0_pack(const int* __restrict__ adj,
                                               uint64* __restrict__ mask64) {
  int t = threadIdx.x;
  int wid = t >> 6, lane = t & 63;
  int row = blockIdx.x * 4 + wid;
  const int* ar = adj + (size_t)row * N_NODES + lane;
  uint64* mr = mask64 + (size_t)row * 96;
  #pragma unroll 8
  for (int c = 0; c < 96; ++c) {
    int v = ar[c << 6];
    uint64 b = __ballot(v != 0);
    if (lane == (c & 63)) mr[c] = b;
  }
}

// K1: h = x*W (fp32). hfT (bf16 [c][n]) coalesced via LDS transpose;
// s_src2/s_dst2 = (h . a_{src,dst}) * log2(e).
__global__ __launch_bounds__(256) void k1_feat(const float* __restrict__ x,
                                               const float* __restrict__ W,
                                               const float* __restrict__ a,
                                               unsigned short* __restrict__ hfT,
                                               float* __restrict__ s_src2,
                                               float* __restrict__ s_dst2) {
  __shared__ float xl[64][132];
  __shared__ float Wl[64][128];
  int t = threadIdx.x;
  int n0 = blockIdx.x * 64;
  for (int u = t; u < 2048; u += 256) {
    int row = u >> 5, c4 = (u & 31) << 2;
    *(float4*)&xl[row][c4] = *(const float4*)(x + (size_t)(n0 + row) * 128 + c4);
  }
  int cg = t & 31, c0 = cg << 2;
  int ng = t >> 5, nb = ng << 3;
  float acc[8][4] = {};
  for (int ic = 0; ic < 2; ++ic) {
    __syncthreads();
    for (int u = t; u < 2048; u += 256) {
      int ii = u >> 5, c4 = (u & 31) << 2;
      int hh = c4 >> 5, d0 = c4 & 31;
      *(float4*)&Wl[ii][c4] = *(const float4*)(W + hh * 4096 + (ic * 64 + ii) * 32 + d0);
    }
    __syncthreads();
    #pragma unroll 4
    for (int ii = 0; ii < 64; ++ii) {
      float4 wv = *(float4*)&Wl[ii][c0];
      int i = ic * 64 + ii;
      #pragma unroll
      for (int r = 0; r < 8; ++r) {
        float xv = xl[nb + r][i];
        acc[r][0] += xv * wv.x; acc[r][1] += xv * wv.y;
        acc[r][2] += xv * wv.z; acc[r][3] += xv * wv.w;
      }
    }
  }
  __syncthreads();
  unsigned short* tb = (unsigned short*)&xl[0][0];   // bf16 [128][66]
  float* pb = &Wl[0][0];                             // float [2][64][33]
  int hh = c0 >> 5, d0 = c0 & 31;
  float4 adv = *(const float4*)(a + hh * 64 + d0);
  float4 asv = *(const float4*)(a + hh * 64 + 32 + d0);
  #pragma unroll
  for (int cc = 0; cc < 4; ++cc) {
    unsigned int* dst = (unsigned int*)(tb + (c0 + cc) * 66 + nb);
    #pragma unroll
    for (int p = 0; p < 4; ++p)
      dst[p] = pack2bf(acc[2 * p][cc], acc[2 * p + 1][cc]);
  }
  #pragma unroll
  for (int r = 0; r < 8; ++r) {
    float pd = acc[r][0] * adv.x + acc[r][1] * adv.y + acc[r][2] * adv.z + acc[r][3] * adv.w;
    float ps = acc[r][0] * asv.x + acc[r][1] * asv.y + acc[r][2] * asv.z + acc[r][3] * asv.w;
    pb[(nb + r) * 33 + cg] = pd;
    pb[2112 + (nb + r) * 33 + cg] = ps;
  }
  __syncthreads();
  {
    int row = t >> 1, half = t & 1;
    const unsigned int* s32 = (const unsigned int*)(tb + row * 66 + half * 32);
    unsigned int v[16];
    #pragma unroll
    for (int q = 0; q < 16; ++q) v[q] = s32[q];
    unsigned short* gdst = hfT + (size_t)row * N_NODES + n0 + half * 32;
    #pragma unroll
    for (int q = 0; q < 4; ++q) {
      uint4 w4; w4.x = v[4 * q]; w4.y = v[4 * q + 1]; w4.z = v[4 * q + 2]; w4.w = v[4 * q + 3];
      *(uint4*)(gdst + q * 8) = w4;
    }
  }
  for (int task = t; task < 512; task += 256) {
    int n = task & 63, hz = task >> 6;
    int h = hz & 3, sdx = hz >> 2;
    const float* src = pb + sdx * 2112 + n * 33 + h * 8;
    float s = src[0] + src[1] + src[2] + src[3] + src[4] + src[5] + src[6] + src[7];
    float* out = sdx ? s_src2 : s_dst2;
    out[h * N_NODES + n0 + n] = s * LOG2E;
  }
}

// one m-tile k-step: weights in A-layout, 2 value-MFMAs + 1 z-MFMA (ones B)
__device__ __forceinline__ void gat_tile(float ss, uint32 bits8,
                                         const float (&dv)[8], short8 b0, short8 b1,
                                         short8 ones, f32x4& a0, f32x4& a1, f32x4& az) {
  float w[8];
  #pragma unroll
  for (int j = 0; j < 8; ++j) {
    float e = ss + dv[j];                    // (s_src+s_dst) * log2e
    float lr = fmaxf(e, 0.2f * e);           // leaky-relu (log2 domain)
    float ex = __ocml_native_exp2_f32(lr);   // v_exp_f32
    w[j] = (bits8 & (1u << j)) ? ex : 0.f;
  }
  union { uint32 u4[4]; short8 v; } afr;
  #pragma unroll
  for (int j = 0; j < 4; ++j) afr.u4[j] = pack2bf(w[2 * j], w[2 * j + 1]);
  a0 = __builtin_amdgcn_mfma_f32_16x16x32_bf16(afr.v, b0, a0, 0, 0, 0);
  a1 = __builtin_amdgcn_mfma_f32_16x16x32_bf16(afr.v, b1, a1, 0, 0, 0);
  az = __builtin_amdgcn_mfma_f32_16x16x32_bf16(afr.v, ones, az, 0, 0, 0);
}

// load burst for one 4-step group: 2 mask uint4 + 8 hfT int4 (named members)
struct Burst {
  uint4 M0, M1;
  int4 B00, B01, B10, B11, B20, B21, B30, B31;
};

__device__ __forceinline__ Burst load_burst(const uint32* mr0, const uint32* mr1,
                                            const unsigned short* hp0,
                                            const unsigned short* hp1, int o) {
  Burst b;
  int ko = o << 7;
  b.M0 = *(const uint4*)(mr0 + (o << 2));
  b.M1 = *(const uint4*)(mr1 + (o << 2));
  b.B00 = *(const int4*)(hp0 + ko);      b.B01 = *(const int4*)(hp1 + ko);
  b.B10 = *(const int4*)(hp0 + ko + 32); b.B11 = *(const int4*)(hp1 + ko + 32);
  b.B20 = *(const int4*)(hp0 + ko + 64); b.B21 = *(const int4*)(hp1 + ko + 64);
  b.B30 = *(const int4*)(hp0 + ko + 96); b.B31 = *(const int4*)(hp1 + ko + 96);
  return b;
}

// one k-step across the 2 m-tiles (shared d/B operands)
__device__ __forceinline__ void step2(uint32 w0, uint32 w1,
                                      int sh, const float* sdp, int koff,
                                      int4 B0i, int4 B1i, short8 ones,
                                      float ss0, float ss1,
                                      f32x4& a00, f32x4& a01, f32x4& a10, f32x4& a11,
                                      f32x4& az0, f32x4& az1) {
  f32x4 d0 = *(const f32x4*)(sdp + koff);
  f32x4 d1 = *(const f32x4*)(sdp + koff + 4);
  float dv[8] = {d0[0], d0[1], d0[2], d0[3], d1[0], d1[1], d1[2], d1[3]};
  union { int4 i; short8 v; } b0u, b1u;
  b0u.i = B0i; b1u.i = B1i;
  gat_tile(ss0, (w0 >> sh) & 0xffu, dv, b0u.v, b1u.v, ones, a00, a01, az0);
  gat_tile(ss1, (w1 >> sh) & 0xffu, dv, b0u.v, b1u.v, ones, a10, a11, az1);
}

__device__ __forceinline__ void compute_burst(const Burst& b, int sh,
                                              const float* sdp, int o, short8 ones,
                                              float ss0, float ss1,
                                              f32x4& a00, f32x4& a01,
                                              f32x4& a10, f32x4& a11,
                                              f32x4& az0, f32x4& az1) {
  int ko = o << 7;
  step2(b.M0.x, b.M1.x, sh, sdp, ko,      b.B00, b.B01, ones, ss0, ss1,
        a00, a01, a10, a11, az0, az1);
  step2(b.M0.y, b.M1.y, sh, sdp, ko + 32, b.B10, b.B11, ones, ss0, ss1,
        a00, a01, a10, a11, az0, az1);
  step2(b.M0.z, b.M1.z, sh, sdp, ko + 64, b.B20, b.B21, ones, ss0, ss1,
        a00, a01, a10, a11, az0, az1);
  step2(b.M0.w, b.M1.w, sh, sdp, ko + 96, b.B30, b.B31, ones, ss0, ss1,
        a00, a01, a10, a11, az0, az1);
}

// K2: fused masked-softmax aggregate. Block = 4 waves = 4 heads x 32 rows
// (2 m-tiles) x k-slice 768 (split 8) -> 1536 blocks. Fully-unrolled
// 6-group SSA software pipeline, depth 1: each load burst is issued one
// full compute-group (~830 cyc) before its consumer, so the compiler's
// waitcnt resolves as vmcnt(10) (prior burst done, next still in flight)
// instead of vmcnt(0) — the hipBLASLt-style never-drain pattern.
__global__ __launch_bounds__(256, 3) void k2_attn(const uint32* __restrict__ maskw,
                                                  const unsigned short* __restrict__ hfT,
                                                  const float* __restrict__ s_src2,
                                                  const float* __restrict__ s_dst2,
                                                  float* __restrict__ Zpart,
                                                  float* __restrict__ part) {
  __shared__ float sd[4][768];   // 12 KB
  int t = threadIdx.x;
  int h = t >> 6, lane = t & 63, m = lane & 15, quad = lane >> 4;
  int sh = quad << 3;
  int bx = blockIdx.x;
  int slice = bx & 7, mg = bx >> 3;
  int i0 = mg << 5, kbase = slice * 768;   // 32 rows per block
  {
    const float4* g = (const float4*)s_dst2;
    float4* l = (float4*)sd;
    int kb4 = kbase >> 2;
    #pragma unroll
    for (int r = 0; r < 3; ++r) {
      int u = t + (r << 8);
      int hx = u / 192, uu = u - hx * 192;
      l[hx * 192 + uu] = g[hx * 1536 + kb4 + uu];
    }
  }
  float ss0 = s_src2[h * N_NODES + i0 + m];
  float ss1 = s_src2[h * N_NODES + i0 + 16 + m];
  __syncthreads();

  const unsigned short* hp0 = hfT + (size_t)(h * 32 + m) * N_NODES + kbase + sh;
  const unsigned short* hp1 = hp0 + (size_t)16 * N_NODES;
  const uint32* mr0 = maskw + (size_t)(i0 + m) * 192 + slice * 24;
  const uint32* mr1 = mr0 + 16 * 192;
  const float* sdp = &sd[h][0] + sh;

  f32x4 a00 = {0,0,0,0}, a01 = {0,0,0,0};
  f32x4 a10 = {0,0,0,0}, a11 = {0,0,0,0};
  f32x4 az0 = {0,0,0,0}, az1 = {0,0,0,0};
  union { uint32 u[4]; short8 v; } ones;
  #pragma unroll
  for (int q = 0; q < 4; ++q) ones.u[q] = 0x3F803F80u;

  // ---- fully-unrolled depth-1 software pipeline over the 6 groups ----
  Burst b0 = load_burst(mr0, mr1, hp0, hp1, 0);
  Burst b1 = load_burst(mr0, mr1, hp0, hp1, 1);
  __builtin_amdgcn_sched_barrier(0);
  compute_burst(b0, sh, sdp, 0, ones.v, ss0, ss1, a00, a01, a10, a11, az0, az1);
  Burst b2 = load_burst(mr0, mr1, hp0, hp1, 2);
  __builtin_amdgcn_sched_barrier(0);
  compute_burst(b1, sh, sdp, 1, ones.v, ss0, ss1, a00, a01, a10, a11, az0, az1);
  Burst b3 = load_burst(mr0, mr1, hp0, hp1, 3);
  __builtin_amdgcn_sched_barrier(0);
  compute_burst(b2, sh, sdp, 2, ones.v, ss0, ss1, a00, a01, a10, a11, az0, az1);
  Burst b4 = load_burst(mr0, mr1, hp0, hp1, 4);
  __builtin_amdgcn_sched_barrier(0);
  compute_burst(b3, sh, sdp, 3, ones.v, ss0, ss1, a00, a01, a10, a11, az0, az1);
  Burst b5 = load_burst(mr0, mr1, hp0, hp1, 5);
  __builtin_amdgcn_sched_barrier(0);
  compute_burst(b4, sh, sdp, 4, ones.v, ss0, ss1, a00, a01, a10, a11, az0, az1);
  compute_burst(b5, sh, sdp, 5, ones.v, ss0, ss1, a00, a01, a10, a11, az0, az1);

  // Z per-slice stores: ones-MFMA made every column hold the row sum
  if (m == 0) {
    float* zb = Zpart + (size_t)slice * 24576 + h * N_NODES + i0 + (quad << 2);
    #pragma unroll
    for (int r = 0; r < 4; ++r) {
      zb[r] = az0[r];
      zb[16 + r] = az1[r];
    }
  }
  // partial stores: part[slice][h][row][col]; D: col=lane&15, row=quad*4+reg
  float* pb = part + (size_t)slice * 786432 + (size_t)h * (N_NODES * 32) +
              (size_t)i0 * 32;
  #pragma unroll
  for (int r = 0; r < 4; ++r) {
    int row = (quad << 2) + r;
    pb[row * 32 + m] = a00[r];
    pb[row * 32 + 16 + m] = a01[r];
    pb[(16 + row) * 32 + m] = a10[r];
    pb[(16 + row) * 32 + 16 + m] = a11[r];
  }
}

// K3: out = sum_s part[s] / sum_s Z[s]
__global__ __launch_bounds__(256) void k3_final(const float* __restrict__ part,
                                                const float* __restrict__ Zpart,
                                                float* __restrict__ out) {
  unsigned int idx4 = blockIdx.x * 256 + threadIdx.x;   // float4 index
  unsigned int h = idx4 / 49152u;
  unsigned int i = (idx4 - h * 49152u) >> 3;
  float z = 0.f;
  #pragma unroll
  for (int s = 0; s < 8; ++s) z += Zpart[s * 24576u + h * N_NODES + i];
  f32x4 p = {0.f, 0.f, 0.f, 0.f};
  const f32x4* P = (const f32x4*)part;
  #pragma unroll
  for (int s = 0; s < 8; ++s) p += P[(size_t)s * 196608u + idx4];
  float rz = 1.0f / z;
  ((f32x4*)out)[idx4] = p * rz;
}

extern "C" void kernel_launch(void* const* d_in, const int* in_sizes, int n_in,
                              void* d_out, int out_size, void* d_ws, size_t ws_size,
                              hipStream_t stream) {
  const float* x = (const float*)d_in[0];
  const int* adj = (const int*)d_in[1];
  const float* W = (const float*)d_in[2];
  const float* a = (const float*)d_in[3];
  float* out = (float*)d_out;

  float* wsf = (float*)d_ws;
  unsigned short* hfT = (unsigned short*)wsf;       // 128*6144 bf16 (1.5 MB)
  float* s_src2 = wsf + 393216;                     // 4*6144
  float* s_dst2 = s_src2 + 24576;                   // 4*6144
  float* part   = s_dst2 + 24576;                   // 8 slices * 786432 (24 MB)
  float* Zpart  = part + 8 * 786432;                // 8 slices * 24576
  uint64* mask64 = (uint64*)(Zpart + 8 * 24576);    // 6144*96 u64 (4.7 MB)

  hipLaunchKernelGGL(k0_pack, dim3(1536), dim3(256), 0, stream, adj, mask64);
  hipLaunchKernelGGL(k1_feat, dim3(96), dim3(256), 0, stream, x, W, a, hfT, s_src2, s_dst2);
  hipLaunchKernelGGL(k2_attn, dim3(1536), dim3(256), 0, stream,
                     (const uint32*)mask64, hfT, s_src2, s_dst2, Zpart, part);
  hipLaunchKernelGGL(k3_final, dim3(768), dim3(256), 0, stream, part, Zpart, out);
}

// Round 14
// 308.398 us; speedup vs baseline: 1.0218x; 1.0218x over previous
//
#include <hip/hip_runtime.h>
#include <stdint.h>

#define N_NODES 6144
#define LOG2E 1.44269504088896f

typedef float f32x4 __attribute__((ext_vector_type(4)));
typedef short short8 __attribute__((ext_vector_type(8)));
typedef unsigned int uint32;
typedef unsigned long long uint64;

extern "C" __device__ float __ocml_native_exp2_f32(float);

// pack two floats -> two bf16 (round-half-up) in one u32: lo=a, hi=b
__device__ __forceinline__ unsigned int pack2bf(float a, float b) {
  unsigned int ua = __float_as_uint(a) + 0x8000u;
  unsigned int ub = __float_as_uint(b) + 0x8000u;
  return __builtin_amdgcn_perm(ub, ua, 0x07060302u);
}

// K0: bit-pack adjacency via wave ballot. Lane reads ONE int (coalesced
// 256B per wave instr), ballot packs 64 edges, one lane stores the u64.
__global__ __launch_bounds__(256) void k0_pack(const int* __restrict__ adj,
                                               uint64* __restrict__ mask64) {
  int t = threadIdx.x;
  int wid = t >> 6, lane = t & 63;
  int row = blockIdx.x * 4 + wid;
  const int* ar = adj + (size_t)row * N_NODES + lane;
  uint64* mr = mask64 + (size_t)row * 96;
  #pragma unroll 8
  for (int c = 0; c < 96; ++c) {
    int v = ar[c << 6];
    uint64 b = __ballot(v != 0);
    if (lane == (c & 63)) mr[c] = b;
  }
}

// K1: h = x*W (fp32). Features written in fragment-major layout
// hfF[h][kb32][frag][lane] (int4 per lane = exact MFMA B-fragment),
// so K2's loads are lane-contiguous. s_*2 = (h . a_*) * log2(e).
__global__ __launch_bounds__(256) void k1_feat(const float* __restrict__ x,
                                               const float* __restrict__ W,
                                               const float* __restrict__ a,
                                               unsigned short* __restrict__ hfF,
                                               float* __restrict__ s_src2,
                                               float* __restrict__ s_dst2) {
  __shared__ float xl[64][132];
  __shared__ float Wl[64][128];
  int t = threadIdx.x;
  int n0 = blockIdx.x * 64;
  for (int u = t; u < 2048; u += 256) {
    int row = u >> 5, c4 = (u & 31) << 2;
    *(float4*)&xl[row][c4] = *(const float4*)(x + (size_t)(n0 + row) * 128 + c4);
  }
  int cg = t & 31, c0 = cg << 2;
  int ng = t >> 5, nb = ng << 3;
  float acc[8][4] = {};
  for (int ic = 0; ic < 2; ++ic) {
    __syncthreads();
    for (int u = t; u < 2048; u += 256) {
      int ii = u >> 5, c4 = (u & 31) << 2;
      int hh = c4 >> 5, d0 = c4 & 31;
      *(float4*)&Wl[ii][c4] = *(const float4*)(W + hh * 4096 + (ic * 64 + ii) * 32 + d0);
    }
    __syncthreads();
    #pragma unroll 4
    for (int ii = 0; ii < 64; ++ii) {
      float4 wv = *(float4*)&Wl[ii][c0];
      int i = ic * 64 + ii;
      #pragma unroll
      for (int r = 0; r < 8; ++r) {
        float xv = xl[nb + r][i];
        acc[r][0] += xv * wv.x; acc[r][1] += xv * wv.y;
        acc[r][2] += xv * wv.z; acc[r][3] += xv * wv.w;
      }
    }
  }
  __syncthreads();
  unsigned short* tb = (unsigned short*)&xl[0][0];   // bf16 [128 cols][66 nodes]
  float* pb = &Wl[0][0];                             // float [2][64][33]
  int hh = c0 >> 5, d0 = c0 & 31;
  float4 adv = *(const float4*)(a + hh * 64 + d0);
  float4 asv = *(const float4*)(a + hh * 64 + 32 + d0);
  #pragma unroll
  for (int cc = 0; cc < 4; ++cc) {
    unsigned int* dst = (unsigned int*)(tb + (c0 + cc) * 66 + nb);
    #pragma unroll
    for (int p = 0; p < 4; ++p)
      dst[p] = pack2bf(acc[2 * p][cc], acc[2 * p + 1][cc]);
  }
  #pragma unroll
  for (int r = 0; r < 8; ++r) {
    float pd = acc[r][0] * adv.x + acc[r][1] * adv.y + acc[r][2] * adv.z + acc[r][3] * adv.w;
    float ps = acc[r][0] * asv.x + acc[r][1] * asv.y + acc[r][2] * asv.z + acc[r][3] * asv.w;
    pb[(nb + r) * 33 + cg] = pd;
    pb[2112 + (nb + r) * 33 + cg] = ps;
  }
  __syncthreads();
  // fragment-major store: chunk = (h, kb_local, f); lane holds
  // cols f*16+m of head h, nodes kb*32 + quad*8 .. +8  (int4 = 8 bf16)
  {
    #pragma unroll
    for (int p = 0; p < 4; ++p) {
      int chunk = (p << 2) + (t >> 6);
      int lane = t & 63, mm = lane & 15, qq = lane >> 4;
      int h2 = chunk >> 2, kbl = (chunk >> 1) & 1, ff = chunk & 1;
      const unsigned int* s32 = (const unsigned int*)(
          tb + (h2 * 32 + ff * 16 + mm) * 66 + kbl * 32 + (qq << 3));
      int4 v;
      v.x = s32[0]; v.y = s32[1]; v.z = s32[2]; v.w = s32[3];
      int kbg = (n0 >> 5) + kbl;
      *(int4*)(hfF + (size_t)(((h2 * 192 + kbg) * 2 + ff) * 64 + lane) * 8) = v;
    }
  }
  for (int task = t; task < 512; task += 256) {
    int n = task & 63, hz = task >> 6;
    int h = hz & 3, sdx = hz >> 2;
    const float* src = pb + sdx * 2112 + n * 33 + h * 8;
    float s = src[0] + src[1] + src[2] + src[3] + src[4] + src[5] + src[6] + src[7];
    float* out = sdx ? s_src2 : s_dst2;
    out[h * N_NODES + n0 + n] = s * LOG2E;
  }
}

// one m-tile k-step: weights in A-layout, 2 value-MFMAs + 1 z-MFMA (ones B)
__device__ __forceinline__ void gat_tile(float ss, uint32 bits8,
                                         const float (&dv)[8], short8 b0, short8 b1,
                                         short8 ones, f32x4& a0, f32x4& a1, f32x4& az) {
  float w[8];
  #pragma unroll
  for (int j = 0; j < 8; ++j) {
    float e = ss + dv[j];                    // (s_src+s_dst) * log2e
    float lr = fmaxf(e, 0.2f * e);           // leaky-relu (log2 domain)
    float ex = __ocml_native_exp2_f32(lr);   // v_exp_f32
    w[j] = (bits8 & (1u << j)) ? ex : 0.f;
  }
  union { uint32 u4[4]; short8 v; } afr;
  #pragma unroll
  for (int j = 0; j < 4; ++j) afr.u4[j] = pack2bf(w[2 * j], w[2 * j + 1]);
  a0 = __builtin_amdgcn_mfma_f32_16x16x32_bf16(afr.v, b0, a0, 0, 0, 0);
  a1 = __builtin_amdgcn_mfma_f32_16x16x32_bf16(afr.v, b1, a1, 0, 0, 0);
  az = __builtin_amdgcn_mfma_f32_16x16x32_bf16(afr.v, ones, az, 0, 0, 0);
}

// one k-step across the 2 m-tiles (shared d/B operands)
__device__ __forceinline__ void step2(uint32 w0, uint32 w1,
                                      int sh, const float* sdp, int koff,
                                      int4 B0i, int4 B1i, short8 ones,
                                      float ss0, float ss1,
                                      f32x4& a00, f32x4& a01, f32x4& a10, f32x4& a11,
                                      f32x4& az0, f32x4& az1) {
  f32x4 d0 = *(const f32x4*)(sdp + koff);
  f32x4 d1 = *(const f32x4*)(sdp + koff + 4);
  float dv[8] = {d0[0], d0[1], d0[2], d0[3], d1[0], d1[1], d1[2], d1[3]};
  union { int4 i; short8 v; } b0u, b1u;
  b0u.i = B0i; b1u.i = B1i;
  gat_tile(ss0, (w0 >> sh) & 0xffu, dv, b0u.v, b1u.v, ones, a00, a01, az0);
  gat_tile(ss1, (w1 >> sh) & 0xffu, dv, b0u.v, b1u.v, ones, a10, a11, az1);
}

// K2: fused masked-softmax aggregate. Block = 4 waves = 4 heads x 32 rows
// (2 m-tiles) x k-slice 768 (split 8). ALL hot-loop global loads are now
// lane-contiguous (hfF fragment-major: base + lane*16 = one 1KB coalesced
// request/instr); masks staged to LDS once (3 KB) and read as aligned
// b128 broadcasts. This attacks TA/address-divergence, not latency.
__global__ __launch_bounds__(256, 4) void k2_attn(const uint32* __restrict__ maskw,
                                                  const unsigned short* __restrict__ hfF,
                                                  const float* __restrict__ s_src2,
                                                  const float* __restrict__ s_dst2,
                                                  float* __restrict__ Zpart,
                                                  float* __restrict__ part) {
  __shared__ float sd[4][768];    // 12 KB
  __shared__ uint32 mlds[32 * 24];  // 3 KB
  int t = threadIdx.x;
  int h = t >> 6, lane = t & 63, m = lane & 15, quad = lane >> 4;
  int sh = quad << 3;
  int bx = blockIdx.x;
  int slice = bx & 7, mg = bx >> 3;
  int i0 = mg << 5, kbase = slice * 768;   // 32 rows per block
  {
    const float4* g = (const float4*)s_dst2;
    float4* l = (float4*)sd;
    int kb4 = kbase >> 2;
    #pragma unroll
    for (int r = 0; r < 3; ++r) {
      int u = t + (r << 8);
      int hx = u / 192, uu = u - hx * 192;
      l[hx * 192 + uu] = g[hx * 1536 + kb4 + uu];
    }
  }
  for (int r = t; r < 768; r += 256) {
    int row = r / 24, w = r - row * 24;
    mlds[r] = maskw[(size_t)(i0 + row) * 192 + slice * 24 + w];
  }
  float ss0 = s_src2[h * N_NODES + i0 + m];
  float ss1 = s_src2[h * N_NODES + i0 + 16 + m];
  __syncthreads();

  // fragment base: [h][kb=slice*24 ..][frag][lane] — 1024 shorts per kb
  const unsigned short* hfb = hfF + (size_t)(h * 192 + slice * 24) * 1024 + lane * 8;
  const float* sdp = &sd[h][0] + sh;

  f32x4 a00 = {0,0,0,0}, a01 = {0,0,0,0};
  f32x4 a10 = {0,0,0,0}, a11 = {0,0,0,0};
  f32x4 az0 = {0,0,0,0}, az1 = {0,0,0,0};
  union { uint32 u[4]; short8 v; } ones;
  #pragma unroll
  for (int q = 0; q < 4; ++q) ones.u[q] = 0x3F803F80u;

  #pragma unroll 1
  for (int o = 0; o < 6; ++o) {
    const unsigned short* gb = hfb + o * 4096;   // 4 steps x 2 frags x 512
    int4 B00 = *(const int4*)(gb);
    int4 B01 = *(const int4*)(gb + 512);
    int4 B10 = *(const int4*)(gb + 1024);
    int4 B11 = *(const int4*)(gb + 1536);
    int4 B20 = *(const int4*)(gb + 2048);
    int4 B21 = *(const int4*)(gb + 2560);
    int4 B30 = *(const int4*)(gb + 3072);
    int4 B31 = *(const int4*)(gb + 3584);
    uint4 M0 = *(const uint4*)&mlds[m * 24 + (o << 2)];
    uint4 M1 = *(const uint4*)&mlds[(16 + m) * 24 + (o << 2)];
    __builtin_amdgcn_sched_barrier(0);
    int ko = o << 7;
    step2(M0.x, M1.x, sh, sdp, ko,      B00, B01, ones.v, ss0, ss1,
          a00, a01, a10, a11, az0, az1);
    step2(M0.y, M1.y, sh, sdp, ko + 32, B10, B11, ones.v, ss0, ss1,
          a00, a01, a10, a11, az0, az1);
    step2(M0.z, M1.z, sh, sdp, ko + 64, B20, B21, ones.v, ss0, ss1,
          a00, a01, a10, a11, az0, az1);
    step2(M0.w, M1.w, sh, sdp, ko + 96, B30, B31, ones.v, ss0, ss1,
          a00, a01, a10, a11, az0, az1);
  }

  // Z per-slice stores: ones-MFMA made every column hold the row sum
  if (m == 0) {
    float* zb = Zpart + (size_t)slice * 24576 + h * N_NODES + i0 + (quad << 2);
    #pragma unroll
    for (int r = 0; r < 4; ++r) {
      zb[r] = az0[r];
      zb[16 + r] = az1[r];
    }
  }
  // partial stores: part[slice][h][row][col]; D: col=lane&15, row=quad*4+reg
  float* pb = part + (size_t)slice * 786432 + (size_t)h * (N_NODES * 32) +
              (size_t)i0 * 32;
  #pragma unroll
  for (int r = 0; r < 4; ++r) {
    int row = (quad << 2) + r;
    pb[row * 32 + m] = a00[r];
    pb[row * 32 + 16 + m] = a01[r];
    pb[(16 + row) * 32 + m] = a10[r];
    pb[(16 + row) * 32 + 16 + m] = a11[r];
  }
}

// K3: out = sum_s part[s] / sum_s Z[s]
__global__ __launch_bounds__(256) void k3_final(const float* __restrict__ part,
                                                const float* __restrict__ Zpart,
                                                float* __restrict__ out) {
  unsigned int idx4 = blockIdx.x * 256 + threadIdx.x;   // float4 index
  unsigned int h = idx4 / 49152u;
  unsigned int i = (idx4 - h * 49152u) >> 3;
  float z = 0.f;
  #pragma unroll
  for (int s = 0; s < 8; ++s) z += Zpart[s * 24576u + h * N_NODES + i];
  f32x4 p = {0.f, 0.f, 0.f, 0.f};
  const f32x4* P = (const f32x4*)part;
  #pragma unroll
  for (int s = 0; s < 8; ++s) p += P[(size_t)s * 196608u + idx4];
  float rz = 1.0f / z;
  ((f32x4*)out)[idx4] = p * rz;
}

extern "C" void kernel_launch(void* const* d_in, const int* in_sizes, int n_in,
                              void* d_out, int out_size, void* d_ws, size_t ws_size,
                              hipStream_t stream) {
  const float* x = (const float*)d_in[0];
  const int* adj = (const int*)d_in[1];
  const float* W = (const float*)d_in[2];
  const float* a = (const float*)d_in[3];
  float* out = (float*)d_out;

  float* wsf = (float*)d_ws;
  unsigned short* hfF = (unsigned short*)wsf;       // 4*192*2*64*8 bf16 (1.5 MB)
  float* s_src2 = wsf + 393216;                     // 4*6144
  float* s_dst2 = s_src2 + 24576;                   // 4*6144
  float* part   = s_dst2 + 24576;                   // 8 slices * 786432 (24 MB)
  float* Zpart  = part + 8 * 786432;                // 8 slices * 24576
  uint64* mask64 = (uint64*)(Zpart + 8 * 24576);    // 6144*96 u64 (4.7 MB)

  hipLaunchKernelGGL(k0_pack, dim3(1536), dim3(256), 0, stream, adj, mask64);
  hipLaunchKernelGGL(k1_feat, dim3(96), dim3(256), 0, stream, x, W, a, hfF, s_src2, s_dst2);
  hipLaunchKernelGGL(k2_attn, dim3(1536), dim3(256), 0, stream,
                     (const uint32*)mask64, hfF, s_src2, s_dst2, Zpart, part);
  hipLaunchKernelGGL(k3_final, dim3(768), dim3(256), 0, stream, part, Zpart, out);
}